// Round 5
// baseline (1822.122 us; speedup 1.0000x reference)
//
#include <hip/hip_runtime.h>
#include <math.h>

#define BB 4
#define LL 2048
#define HH 8
#define EE 64
#define TM 64
#define TN 64
#define SH 72   // fp16 LDS row stride

typedef _Float16 half4v __attribute__((ext_vector_type(4)));
typedef _Float16 half8v __attribute__((ext_vector_type(8)));
typedef float floatx4 __attribute__((ext_vector_type(4)));

static constexpr float SCALE = 0.125f;                    // 1/sqrt(64)
static constexpr float LN3 = 1.0986122886681098f;
static constexpr float INV_SQRT_2PI = 0.3989422804014327f;
static constexpr size_t NMAT = (size_t)BB * HH * LL * LL;
static constexpr size_t SERIES_BASE = (size_t)BB * LL * HH * EE;
static constexpr size_t PRIOR_BASE = SERIES_BASE + NMAT;
static constexpr size_t SIG_BASE = PRIOR_BASE + NMAT;

// R0 champion structure (two-pass, 256 thr, TM=TN=64, strip-paired halves) +
// A: prior/sig/zero writes flattened into a 95-chunk queue consumed 2 per
//    j-tile iteration (store drain overlaps compute instead of serial tail)
// C: (x,y)->(bh,strip) swizzle so XCD c hosts only bh === c (mod 8):
//    per-XCD K+V working set ~4 MB -> L2-resident K/V re-reads.
__global__ __launch_bounds__(256, 2)
void anomaly_attn(const float* __restrict__ qg,
                  const float* __restrict__ kg,
                  const float* __restrict__ vg,
                  const float* __restrict__ sgg,
                  float* __restrict__ out) {
  __shared__ __attribute__((aligned(16))) _Float16 Qh[TM * SH];
  __shared__ __attribute__((aligned(16))) _Float16 Kh[TN * SH];
  __shared__ __attribute__((aligned(16))) _Float16 Vt[EE * SH];  // transposed: [e][j]
  __shared__ __attribute__((aligned(16))) _Float16 Ph[TM * SH];
  __shared__ float s_sigv[2 * TM], s_pinv[2 * TM], s_c2[2 * TM];

  const int t = threadIdx.x;
  const int lane = t & 63;
  const int w = t >> 6;          // wave id 0..3 -> rows w*16..w*16+15
  const int quad = lane >> 4;    // 0..3
  const int l15 = lane & 15;

  // ---- C: XCD locality swizzle (XCD = linear%8 = x%8 -> force bh%8 = x%8) ----
  const int rx = blockIdx.x;     // [0,16)
  const int ry = blockIdx.y;     // [0,32)
  const int bh = (rx & 7) | ((ry & 3) << 3);          // [0,32)
  const int st = (rx >> 3) | ((ry >> 2) << 1);        // strip [0,16)
  const int b = bh >> 3, h = bh & 7;
  const int rt0 = st, rt1 = 31 - st;
  const int i00 = rt0 * TM, i01 = rt1 * TM;

  const float4* q4 = (const float4*)qg;
  const float4* k4 = (const float4*)kg;
  const float4* v4 = (const float4*)vg;

  // ---- sigma transform for BOTH halves' rows, once per block ----
  if (t < 128) {
    int hf = t >> 6, rr = t & 63;
    int irow = (hf ? i01 : i00) + rr;
    float sg = sgg[((size_t)b * LL + irow) * HH + h];
    float sd = 1.0f / (1.0f + __expf(-5.0f * sg)) + 1e-5f;
    float sv = expm1f(sd * LN3);     // 3^sd - 1, cancellation-safe
    s_sigv[t] = sv;
    s_pinv[t] = INV_SQRT_2PI / sv;
    s_c2[t] = 0.5f / (sv * sv);
  }

  // ---- A: chunk queue. c<64: prior+sig tile (hf=c>>5, jc=c&31).
  //         c>=64: series zero tile. Total 95, consumed 2/iteration. ----
  int cq = 0;
  const int z0 = 31 - st;   // half0 zero-tile count (half1 has st)
  auto write_chunk = [&](int c) {
    if (c < 64) {
      const int hf = c >> 5;
      const int jc = c & 31;
      const int i0c = hf ? i01 : i00;
#pragma unroll
      for (int u = 0; u < 4; ++u) {
        int idx = t + 256 * u;
        int rr = idx >> 4, cc = idx & 15;
        int sidx = hf * 64 + rr;
        float iv = s_pinv[sidx], c2 = s_c2[sidx], sv = s_sigv[sidx];
        float fi = (float)(i0c + rr);
        float d0 = fi - (float)(jc * 64 + cc * 4);
        float d1 = d0 - 1.0f, d2 = d0 - 2.0f, d3 = d0 - 3.0f;
        floatx4 pr;
        pr.x = iv * __expf(-d0 * d0 * c2);
        pr.y = iv * __expf(-d1 * d1 * c2);
        pr.z = iv * __expf(-d2 * d2 * c2);
        pr.w = iv * __expf(-d3 * d3 * c2);
        size_t off = ((size_t)bh * LL + (i0c + rr)) * LL + jc * 64 + cc * 4;
        __builtin_nontemporal_store(pr, (floatx4*)&out[PRIOR_BASE + off]);
        floatx4 s4 = {sv, sv, sv, sv};
        __builtin_nontemporal_store(s4, (floatx4*)&out[SIG_BASE + off]);
      }
    } else {
      int z = c - 64;
      int hf, jc;
      if (z < z0) { hf = 0; jc = st + 1 + z; }
      else        { hf = 1; jc = z + 1; }
      const int i0c = hf ? i01 : i00;
      const floatx4 zz = {0.f, 0.f, 0.f, 0.f};
#pragma unroll
      for (int u = 0; u < 4; ++u) {
        int idx = t + 256 * u;
        int rr = idx >> 4, cc = idx & 15;
        size_t off = SERIES_BASE + ((size_t)bh * LL + (i0c + rr)) * LL + jc * 64 + cc * 4;
        __builtin_nontemporal_store(zz, (floatx4*)&out[off]);
      }
    }
  };

  for (int half = 0; half < 2; ++half) {
    const int rt = half ? rt1 : rt0;
    const int i0 = rt * TM;
    const int nt = rt + 1;       // causal j-tiles
    __syncthreads();             // protect LDS from previous half's readers

    // ---- stage Q (fp32 -> fp16 LDS, row-major) ----
#pragma unroll
    for (int it = 0; it < 4; ++it) {
      int idx = t + 256 * it;
      int r = idx >> 4, c = idx & 15;
      float4 qv = q4[(((size_t)b * LL + i0 + r) * HH + h) * 16 + c];
      half4v hq = {(_Float16)qv.x, (_Float16)qv.y, (_Float16)qv.z, (_Float16)qv.w};
      *(half4v*)&Qh[r * SH + c * 4] = hq;
    }

    // ================= pass 1: row sums of exp(scale*s) =================
    float lsum[4] = {0.f, 0.f, 0.f, 0.f};
    for (int jt = 0; jt < nt; ++jt) {
      const int j0 = jt * TN;
      __syncthreads();             // prev tile's Kh readers done
#pragma unroll
      for (int it = 0; it < 4; ++it) {
        int idx = t + 256 * it;
        int r = idx >> 4, c = idx & 15;
        float4 kv = k4[(((size_t)b * LL + j0 + r) * HH + h) * 16 + c];
        half4v hk = {(_Float16)kv.x, (_Float16)kv.y, (_Float16)kv.z, (_Float16)kv.w};
        *(half4v*)&Kh[r * SH + c * 4] = hk;
      }
      __syncthreads();
      floatx4 acc[4] = {{0.f, 0.f, 0.f, 0.f}, {0.f, 0.f, 0.f, 0.f},
                        {0.f, 0.f, 0.f, 0.f}, {0.f, 0.f, 0.f, 0.f}};
#pragma unroll
      for (int ks = 0; ks < 2; ++ks) {
        half8v a = *(half8v*)&Qh[(w * 16 + l15) * SH + ks * 32 + quad * 8];
#pragma unroll
        for (int f = 0; f < 4; ++f) {
          half8v bf = *(half8v*)&Kh[(f * 16 + l15) * SH + ks * 32 + quad * 8];
          acc[f] = __builtin_amdgcn_mfma_f32_16x16x32_f16(a, bf, acc[f], 0, 0, 0);
        }
      }
#pragma unroll
      for (int f = 0; f < 4; ++f) {
        int j = j0 + f * 16 + l15;        // C col = lane&15
#pragma unroll
        for (int r = 0; r < 4; ++r) {
          int i = i0 + w * 16 + quad * 4 + r;  // C row = quad*4+reg
          lsum[r] += (j <= i) ? __expf(acc[f][r] * SCALE) : 0.f;
        }
      }
      // A: overlap streaming chunk writes with the loop
      if (cq < 95) write_chunk(cq++);
      if (cq < 95) write_chunk(cq++);
    }
#pragma unroll
    for (int r = 0; r < 4; ++r) {
      lsum[r] += __shfl_xor(lsum[r], 1);
      lsum[r] += __shfl_xor(lsum[r], 2);
      lsum[r] += __shfl_xor(lsum[r], 4);
      lsum[r] += __shfl_xor(lsum[r], 8);
    }
    float linv[4];
#pragma unroll
    for (int r = 0; r < 4; ++r) linv[r] = 1.0f / lsum[r];

    // ================= pass 2: series + PV =================
    floatx4 Oacc[4] = {{0.f, 0.f, 0.f, 0.f}, {0.f, 0.f, 0.f, 0.f},
                       {0.f, 0.f, 0.f, 0.f}, {0.f, 0.f, 0.f, 0.f}};
    for (int jt = 0; jt < nt; ++jt) {
      const int j0 = jt * TN;
      __syncthreads();             // prev tile's Ph/Vt/Kh readers done
#pragma unroll
      for (int it = 0; it < 4; ++it) {
        int idx = t + 256 * it;
        int r = idx >> 4, c = idx & 15;
        float4 kv = k4[(((size_t)b * LL + j0 + r) * HH + h) * 16 + c];
        half4v hk = {(_Float16)kv.x, (_Float16)kv.y, (_Float16)kv.z, (_Float16)kv.w};
        *(half4v*)&Kh[r * SH + c * 4] = hk;
      }
      // V staged transposed: thread (tx=e-group, ty=j-group) does 4x4 micro-transpose
      {
        const int tx = t & 15, ty = t >> 4;
        float4 vv[4];
#pragma unroll
        for (int rr = 0; rr < 4; ++rr)
          vv[rr] = v4[(((size_t)b * LL + j0 + ty * 4 + rr) * HH + h) * 16 + tx];
#pragma unroll
        for (int c = 0; c < 4; ++c) {
          float e0 = c == 0 ? vv[0].x : c == 1 ? vv[0].y : c == 2 ? vv[0].z : vv[0].w;
          float e1 = c == 0 ? vv[1].x : c == 1 ? vv[1].y : c == 2 ? vv[1].z : vv[1].w;
          float e2 = c == 0 ? vv[2].x : c == 1 ? vv[2].y : c == 2 ? vv[2].z : vv[2].w;
          float e3 = c == 0 ? vv[3].x : c == 1 ? vv[3].y : c == 2 ? vv[3].z : vv[3].w;
          half4v hv = {(_Float16)e0, (_Float16)e1, (_Float16)e2, (_Float16)e3};
          *(half4v*)&Vt[(tx * 4 + c) * SH + ty * 4] = hv;
        }
      }
      __syncthreads();
      floatx4 acc[4] = {{0.f, 0.f, 0.f, 0.f}, {0.f, 0.f, 0.f, 0.f},
                        {0.f, 0.f, 0.f, 0.f}, {0.f, 0.f, 0.f, 0.f}};
#pragma unroll
      for (int ks = 0; ks < 2; ++ks) {
        half8v a = *(half8v*)&Qh[(w * 16 + l15) * SH + ks * 32 + quad * 8];
#pragma unroll
        for (int f = 0; f < 4; ++f) {
          half8v bf = *(half8v*)&Kh[(f * 16 + l15) * SH + ks * 32 + quad * 8];
          acc[f] = __builtin_amdgcn_mfma_f32_16x16x32_f16(a, bf, acc[f], 0, 0, 0);
        }
      }
      // P = exp(s*scale)*linv (normalized) -> Ph fp16, C->A layout transform
#pragma unroll
      for (int f = 0; f < 4; ++f) {
        int j = j0 + f * 16 + l15;
#pragma unroll
        for (int r = 0; r < 4; ++r) {
          int i = i0 + w * 16 + quad * 4 + r;
          float p = (j <= i) ? __expf(acc[f][r] * SCALE) * linv[r] : 0.f;
          Ph[(w * 16 + quad * 4 + r) * SH + f * 16 + l15] = (_Float16)p;
        }
      }
      __syncthreads();
      // series tile store: coalesced b128 readback -> 2x float4 (NT)
#pragma unroll
      for (int rnd = 0; rnd < 2; ++rnd) {
        int idx = t + 256 * rnd;
        int r = idx >> 3, c8 = idx & 7;
        half8v p = *(half8v*)&Ph[r * SH + c8 * 8];
        floatx4 lo = {(float)p[0], (float)p[1], (float)p[2], (float)p[3]};
        floatx4 hi = {(float)p[4], (float)p[5], (float)p[6], (float)p[7]};
        size_t off = SERIES_BASE + ((size_t)bh * LL + i0 + r) * LL + j0 + c8 * 8;
        __builtin_nontemporal_store(lo, (floatx4*)&out[off]);
        __builtin_nontemporal_store(hi, (floatx4*)&out[off + 4]);
      }
      // PV: O += P * V  (A = Ph rows, B = Vt rows)
#pragma unroll
      for (int ks = 0; ks < 2; ++ks) {
        half8v a = *(half8v*)&Ph[(w * 16 + l15) * SH + ks * 32 + quad * 8];
#pragma unroll
        for (int f = 0; f < 4; ++f) {
          half8v bv = *(half8v*)&Vt[(f * 16 + l15) * SH + ks * 32 + quad * 8];
          Oacc[f] = __builtin_amdgcn_mfma_f32_16x16x32_f16(a, bv, Oacc[f], 0, 0, 0);
        }
      }
      // A: overlap streaming chunk writes with the loop
      if (cq < 95) write_chunk(cq++);
      if (cq < 95) write_chunk(cq++);
    }
    // ---- V output (already normalized) ----
#pragma unroll
    for (int f = 0; f < 4; ++f) {
#pragma unroll
      for (int r = 0; r < 4; ++r) {
        int i = i0 + w * 16 + quad * 4 + r;
        out[(((size_t)b * LL + i) * HH + h) * EE + f * 16 + l15] = Oacc[f][r];
      }
    }
  }
  // drain any remaining chunks (unreachable for all strips: 132 slots >= 95,
  // min causal iters = 2*(1+32)=66 -> 132; kept for safety)
  while (cq < 95) write_chunk(cq++);
}

extern "C" void kernel_launch(void* const* d_in, const int* in_sizes, int n_in,
                              void* d_out, int out_size, void* d_ws, size_t ws_size,
                              hipStream_t stream) {
  const float* q = (const float*)d_in[0];
  const float* k = (const float*)d_in[1];
  const float* v = (const float*)d_in[2];
  const float* sg = (const float*)d_in[3];
  float* out = (float*)d_out;
  dim3 grid(LL / TM / 2, BB * HH);  // 16 x 32 = 512 blocks, strip-paired + swizzled
  anomaly_attn<<<grid, 256, 0, stream>>>(q, k, v, sg, out);
}

// Round 6
// 1750.472 us; speedup vs baseline: 1.0409x; 1.0409x over previous
//
#include <hip/hip_runtime.h>
#include <math.h>

#define BB 4
#define LL 2048
#define HH 8
#define EE 64
#define TM 128
#define TN 64
#define SH 72   // fp16 LDS row stride: 36 dwords -> 4-bank offset per row

typedef _Float16 half4v __attribute__((ext_vector_type(4)));
typedef _Float16 half8v __attribute__((ext_vector_type(8)));
typedef float floatx4 __attribute__((ext_vector_type(4)));

static constexpr float SCALE = 0.125f;                    // 1/sqrt(64)
static constexpr float LN3 = 1.0986122886681098f;
static constexpr float INV_SQRT_2PI = 0.3989422804014327f;
static constexpr size_t NMAT = (size_t)BB * HH * LL * LL;
static constexpr size_t SERIES_BASE = (size_t)BB * LL * HH * EE;
static constexpr size_t PRIOR_BASE = SERIES_BASE + NMAT;
static constexpr size_t SIG_BASE = PRIOR_BASE + NMAT;

// R0 champion numerics, TM doubled to 128: K/V staging amortized over 2x Q
// rows; barrier intervals per CU 132 -> 68. 512 thr / 8 waves, each wave owns
// 16 rows (per-wave code identical to R0). grid(8,32)=256 blocks = 1/CU,
// strip-paired halves (rt = bx, 15-bx) -> uniform 34 intervals per pass.
__global__ __launch_bounds__(512, 2)
void anomaly_attn(const float* __restrict__ qg,
                  const float* __restrict__ kg,
                  const float* __restrict__ vg,
                  const float* __restrict__ sgg,
                  float* __restrict__ out) {
  __shared__ __attribute__((aligned(16))) _Float16 Qh[TM * SH];  // 18432 B
  __shared__ __attribute__((aligned(16))) _Float16 Kh[TN * SH];  //  9216 B
  __shared__ __attribute__((aligned(16))) _Float16 Vt[EE * SH];  //  9216 B (transposed [e][j])
  __shared__ __attribute__((aligned(16))) _Float16 Ph[TM * SH];  // 18432 B
  __shared__ float s_sigv[TM], s_pinv[TM], s_c2[TM];

  const int t = threadIdx.x;
  const int lane = t & 63;
  const int w = t >> 6;          // wave id 0..7 -> rows w*16..w*16+15
  const int quad = lane >> 4;    // 0..3
  const int l15 = lane & 15;
  const int bh = blockIdx.y;
  const int b = bh >> 3, h = bh & 7;
  const float4* q4 = (const float4*)qg;
  const float4* k4 = (const float4*)kg;
  const float4* v4 = (const float4*)vg;

  for (int half = 0; half < 2; ++half) {
    const int rt = half ? (15 - (int)blockIdx.x) : (int)blockIdx.x;  // [0,16)
    const int i0 = rt * TM;
    const int nt = 2 * rt + 2;   // causal 64-col j-tiles for this 128-row tile
    __syncthreads();             // protect LDS/s_* from previous half's readers

    // ---- stage Q (128x64 fp32 -> fp16 LDS): 2048 float4 units / 512 thr ----
#pragma unroll
    for (int it = 0; it < 4; ++it) {
      int idx = t + 512 * it;
      int r = idx >> 4, c = idx & 15;
      float4 qv = q4[(((size_t)b * LL + i0 + r) * HH + h) * 16 + c];
      half4v hq = {(_Float16)qv.x, (_Float16)qv.y, (_Float16)qv.z, (_Float16)qv.w};
      *(half4v*)&Qh[r * SH + c * 4] = hq;
    }
    // ---- per-row sigma transform (for prior/sig tail) ----
    if (t < TM) {
      float sg = sgg[((size_t)b * LL + (i0 + t)) * HH + h];
      float sd = 1.0f / (1.0f + __expf(-5.0f * sg)) + 1e-5f;
      float sv = expm1f(sd * LN3);     // 3^sd - 1, cancellation-safe
      s_sigv[t] = sv;
      s_pinv[t] = INV_SQRT_2PI / sv;
      s_c2[t] = 0.5f / (sv * sv);
    }

    // ================= pass 1: row sums of exp(scale*s) =================
    float lsum[4] = {0.f, 0.f, 0.f, 0.f};
    for (int jt = 0; jt < nt; ++jt) {
      const int j0 = jt * TN;
      __syncthreads();             // prev tile's Kh readers done
      // stage K: 64 rows x 16 float4 = 1024 units / 512 thr
#pragma unroll
      for (int it = 0; it < 2; ++it) {
        int idx = t + 512 * it;
        int r = idx >> 4, c = idx & 15;
        float4 kv = k4[(((size_t)b * LL + j0 + r) * HH + h) * 16 + c];
        half4v hk = {(_Float16)kv.x, (_Float16)kv.y, (_Float16)kv.z, (_Float16)kv.w};
        *(half4v*)&Kh[r * SH + c * 4] = hk;
      }
      __syncthreads();
      floatx4 acc[4] = {{0.f, 0.f, 0.f, 0.f}, {0.f, 0.f, 0.f, 0.f},
                        {0.f, 0.f, 0.f, 0.f}, {0.f, 0.f, 0.f, 0.f}};
#pragma unroll
      for (int ks = 0; ks < 2; ++ks) {
        half8v a = *(half8v*)&Qh[(w * 16 + l15) * SH + ks * 32 + quad * 8];
#pragma unroll
        for (int f = 0; f < 4; ++f) {
          half8v bf = *(half8v*)&Kh[(f * 16 + l15) * SH + ks * 32 + quad * 8];
          acc[f] = __builtin_amdgcn_mfma_f32_16x16x32_f16(a, bf, acc[f], 0, 0, 0);
        }
      }
#pragma unroll
      for (int f = 0; f < 4; ++f) {
        int j = j0 + f * 16 + l15;        // C col = lane&15
#pragma unroll
        for (int r = 0; r < 4; ++r) {
          int i = i0 + w * 16 + quad * 4 + r;  // C row = quad*4+reg
          lsum[r] += (j <= i) ? __expf(acc[f][r] * SCALE) : 0.f;
        }
      }
    }
    // each wave fully owns its 16 rows: reduce across the 16 j-lanes only
#pragma unroll
    for (int r = 0; r < 4; ++r) {
      lsum[r] += __shfl_xor(lsum[r], 1);
      lsum[r] += __shfl_xor(lsum[r], 2);
      lsum[r] += __shfl_xor(lsum[r], 4);
      lsum[r] += __shfl_xor(lsum[r], 8);
    }
    float linv[4];
#pragma unroll
    for (int r = 0; r < 4; ++r) linv[r] = 1.0f / lsum[r];

    // ================= pass 2: series + PV =================
    floatx4 Oacc[4] = {{0.f, 0.f, 0.f, 0.f}, {0.f, 0.f, 0.f, 0.f},
                       {0.f, 0.f, 0.f, 0.f}, {0.f, 0.f, 0.f, 0.f}};
    for (int jt = 0; jt < nt; ++jt) {
      const int j0 = jt * TN;
      __syncthreads();             // prev tile's Ph/Vt/Kh readers done
      if (t < 256) {
        // waves 0-3: stage V transposed (tx=e-group, ty=j-group), 4x4 micro-transpose
        const int tx = t & 15, ty = t >> 4;
        float4 vv[4];
#pragma unroll
        for (int rr = 0; rr < 4; ++rr)
          vv[rr] = v4[(((size_t)b * LL + j0 + ty * 4 + rr) * HH + h) * 16 + tx];
#pragma unroll
        for (int c = 0; c < 4; ++c) {
          float e0 = c == 0 ? vv[0].x : c == 1 ? vv[0].y : c == 2 ? vv[0].z : vv[0].w;
          float e1 = c == 0 ? vv[1].x : c == 1 ? vv[1].y : c == 2 ? vv[1].z : vv[1].w;
          float e2 = c == 0 ? vv[2].x : c == 1 ? vv[2].y : c == 2 ? vv[2].z : vv[2].w;
          float e3 = c == 0 ? vv[3].x : c == 1 ? vv[3].y : c == 2 ? vv[3].z : vv[3].w;
          half4v hv = {(_Float16)e0, (_Float16)e1, (_Float16)e2, (_Float16)e3};
          *(half4v*)&Vt[(tx * 4 + c) * SH + ty * 4] = hv;
        }
      } else {
        // waves 4-7: stage K (1024 units / 256 thr)
        const int tk = t - 256;
#pragma unroll
        for (int it = 0; it < 4; ++it) {
          int idx = tk + 256 * it;
          int r = idx >> 4, c = idx & 15;
          float4 kv = k4[(((size_t)b * LL + j0 + r) * HH + h) * 16 + c];
          half4v hk = {(_Float16)kv.x, (_Float16)kv.y, (_Float16)kv.z, (_Float16)kv.w};
          *(half4v*)&Kh[r * SH + c * 4] = hk;
        }
      }
      __syncthreads();
      // QK
      floatx4 acc[4] = {{0.f, 0.f, 0.f, 0.f}, {0.f, 0.f, 0.f, 0.f},
                        {0.f, 0.f, 0.f, 0.f}, {0.f, 0.f, 0.f, 0.f}};
#pragma unroll
      for (int ks = 0; ks < 2; ++ks) {
        half8v a = *(half8v*)&Qh[(w * 16 + l15) * SH + ks * 32 + quad * 8];
#pragma unroll
        for (int f = 0; f < 4; ++f) {
          half8v bf = *(half8v*)&Kh[(f * 16 + l15) * SH + ks * 32 + quad * 8];
          acc[f] = __builtin_amdgcn_mfma_f32_16x16x32_f16(a, bf, acc[f], 0, 0, 0);
        }
      }
      // P = exp(s*scale)*linv (normalized) -> Ph fp16 (this wave's 16 rows)
#pragma unroll
      for (int f = 0; f < 4; ++f) {
        int j = j0 + f * 16 + l15;
#pragma unroll
        for (int r = 0; r < 4; ++r) {
          int i = i0 + w * 16 + quad * 4 + r;
          float p = (j <= i) ? __expf(acc[f][r] * SCALE) * linv[r] : 0.f;
          Ph[(w * 16 + quad * 4 + r) * SH + f * 16 + l15] = (_Float16)p;
        }
      }
      // series store: wave-local rows (no barrier; same-wave ds_write->ds_read)
      // 8 lanes x 32B = 256B coalesced segments per row
#pragma unroll
      for (int rnd = 0; rnd < 2; ++rnd) {
        int row = w * 16 + rnd * 8 + (lane >> 3);
        int c8 = lane & 7;
        half8v p = *(half8v*)&Ph[row * SH + c8 * 8];
        floatx4 lo = {(float)p[0], (float)p[1], (float)p[2], (float)p[3]};
        floatx4 hi = {(float)p[4], (float)p[5], (float)p[6], (float)p[7]};
        size_t off = SERIES_BASE + ((size_t)bh * LL + i0 + row) * LL + j0 + c8 * 8;
        *(floatx4*)&out[off] = lo;
        *(floatx4*)&out[off + 4] = hi;
      }
      __syncthreads();             // full-width Ph visible for PV
      // PV: O += P * V  (A = Ph own rows, B = Vt rows)
#pragma unroll
      for (int ks = 0; ks < 2; ++ks) {
        half8v a = *(half8v*)&Ph[(w * 16 + l15) * SH + ks * 32 + quad * 8];
#pragma unroll
        for (int f = 0; f < 4; ++f) {
          half8v bv = *(half8v*)&Vt[(f * 16 + l15) * SH + ks * 32 + quad * 8];
          Oacc[f] = __builtin_amdgcn_mfma_f32_16x16x32_f16(a, bv, Oacc[f], 0, 0, 0);
        }
      }
    }
    // ---- V output (already normalized) ----
#pragma unroll
    for (int f = 0; f < 4; ++f) {
#pragma unroll
      for (int r = 0; r < 4; ++r) {
        int i = i0 + w * 16 + quad * 4 + r;
        out[(((size_t)b * LL + i) * HH + h) * EE + f * 16 + l15] = Oacc[f][r];
      }
    }
    // ---- prior + sig full rows (serial tail — proven best placement) ----
    for (int idx = t; idx < TM * 512; idx += 512) {
      int rr = idx >> 9, jq = idx & 511;
      float iv = s_pinv[rr], c2 = s_c2[rr], sv = s_sigv[rr];
      float fi = (float)(i0 + rr);
      float d0 = fi - (float)(jq * 4);
      float d1 = d0 - 1.0f, d2 = d0 - 2.0f, d3 = d0 - 3.0f;
      floatx4 pr;
      pr.x = iv * __expf(-d0 * d0 * c2);
      pr.y = iv * __expf(-d1 * d1 * c2);
      pr.z = iv * __expf(-d2 * d2 * c2);
      pr.w = iv * __expf(-d3 * d3 * c2);
      size_t off = ((size_t)bh * LL + (i0 + rr)) * LL + jq * 4;
      *(floatx4*)&out[PRIOR_BASE + off] = pr;
      floatx4 sg4 = {sv, sv, sv, sv};
      *(floatx4*)&out[SIG_BASE + off] = sg4;
    }
    // ---- series zero-fill (beyond causal tiles) ----
    {
      int jz = nt * TN;
      int nz4 = (LL - jz) >> 2;
      if (nz4 > 0) {
        const floatx4 z = {0.f, 0.f, 0.f, 0.f};
        for (int rr = 0; rr < TM; ++rr) {
          float* rowp = &out[SERIES_BASE + ((size_t)bh * LL + (i0 + rr)) * LL + jz];
          for (int c = t; c < nz4; c += 512) {
            *(floatx4*)&rowp[c * 4] = z;
          }
        }
      }
    }
  }
}

extern "C" void kernel_launch(void* const* d_in, const int* in_sizes, int n_in,
                              void* d_out, int out_size, void* d_ws, size_t ws_size,
                              hipStream_t stream) {
  const float* q = (const float*)d_in[0];
  const float* k = (const float*)d_in[1];
  const float* v = (const float*)d_in[2];
  const float* sg = (const float*)d_in[3];
  float* out = (float*)d_out;
  dim3 grid(16 / 2, BB * HH);  // 8 x 32 = 256 blocks x 512 thr, strip-paired
  anomaly_attn<<<grid, 512, 0, stream>>>(q, k, v, sg, out);
}

// Round 7
// 1689.510 us; speedup vs baseline: 1.0785x; 1.0361x over previous
//
#include <hip/hip_runtime.h>
#include <math.h>

#define BB 4
#define LL 2048
#define HH 8
#define EE 64
#define TM 64
#define TN 64
#define SH 72   // fp16 LDS row stride

typedef _Float16 half4v __attribute__((ext_vector_type(4)));
typedef _Float16 half8v __attribute__((ext_vector_type(8)));
typedef float floatx4 __attribute__((ext_vector_type(4)));

static constexpr float SCALE = 0.125f;                    // 1/sqrt(64)
static constexpr float LN3 = 1.0986122886681098f;
static constexpr float INV_SQRT_2PI = 0.3989422804014327f;
static constexpr size_t NMAT = (size_t)BB * HH * LL * LL;
static constexpr size_t SERIES_BASE = (size_t)BB * LL * HH * EE;
static constexpr size_t PRIOR_BASE = SERIES_BASE + NMAT;
static constexpr size_t SIG_BASE = PRIOR_BASE + NMAT;

// Producer-release barrier: make this wave's LDS writes visible, sync, and
// pin the scheduler so next-tile ds_reads can't hoist above (rule #18).
// Crucially does NOT drain vmcnt -> global stores / prefetch loads stay in
// flight across the barrier (the T3/T4 mechanism, learn_hip m218).
__device__ __forceinline__ void barrier_release() {
  asm volatile("s_waitcnt lgkmcnt(0)" ::: "memory");
  __builtin_amdgcn_s_barrier();
  __builtin_amdgcn_sched_barrier(0);
}

// R0 champion numerics (two-pass, 256 thr, TM=TN=64, strip-paired halves),
// hot loops rebuilt as 2-phase pipelines: reg-staged K/V, double-buffered
// LDS, ONE raw barrier per interval, zero in-loop vmcnt(0) drains.
__global__ __launch_bounds__(256, 2)
void anomaly_attn(const float* __restrict__ qg,
                  const float* __restrict__ kg,
                  const float* __restrict__ vg,
                  const float* __restrict__ sgg,
                  float* __restrict__ out) {
  __shared__ __attribute__((aligned(16))) _Float16 Qh[TM * SH];       //  9216 B
  __shared__ __attribute__((aligned(16))) _Float16 Kh[2][TN * SH];    // 18432 B
  __shared__ __attribute__((aligned(16))) _Float16 Vt[2][EE * SH];    // 18432 B
  __shared__ __attribute__((aligned(16))) _Float16 Ph[TM * SH];       //  9216 B
  __shared__ float s_sigv[TM], s_pinv[TM], s_c2[TM];

  const int t = threadIdx.x;
  const int lane = t & 63;
  const int w = t >> 6;          // wave id 0..3 -> rows w*16..w*16+15
  const int quad = lane >> 4;    // 0..3
  const int l15 = lane & 15;
  const int bh = blockIdx.y;
  const int b = bh >> 3, h = bh & 7;
  const float4* q4 = (const float4*)qg;
  const float4* k4 = (const float4*)kg;
  const float4* v4 = (const float4*)vg;

  // staging geometry (block-cooperative, same partition as R0)
  const int kr_r0 = t >> 4, kr_c = t & 15;        // K: 4 chunks of (r,c)
  const int vtx = t & 15, vty = t >> 4;           // V: 4x4 micro-transpose

  auto loadK = [&](int j0, float4* kr) {
#pragma unroll
    for (int it = 0; it < 4; ++it)
      kr[it] = k4[(((size_t)b * LL + j0 + kr_r0 + 16 * it) * HH + h) * 16 + kr_c];
  };
  auto writeK = [&](int bufi, const float4* kr) {
#pragma unroll
    for (int it = 0; it < 4; ++it) {
      half4v hk = {(_Float16)kr[it].x, (_Float16)kr[it].y,
                   (_Float16)kr[it].z, (_Float16)kr[it].w};
      *(half4v*)&Kh[bufi][(kr_r0 + 16 * it) * SH + kr_c * 4] = hk;
    }
  };
  auto loadV = [&](int j0, float4* vr) {
#pragma unroll
    for (int rr = 0; rr < 4; ++rr)
      vr[rr] = v4[(((size_t)b * LL + j0 + vty * 4 + rr) * HH + h) * 16 + vtx];
  };
  auto writeV = [&](int bufi, const float4* vr) {
#pragma unroll
    for (int c = 0; c < 4; ++c) {
      float e0 = c == 0 ? vr[0].x : c == 1 ? vr[0].y : c == 2 ? vr[0].z : vr[0].w;
      float e1 = c == 0 ? vr[1].x : c == 1 ? vr[1].y : c == 2 ? vr[1].z : vr[1].w;
      float e2 = c == 0 ? vr[2].x : c == 1 ? vr[2].y : c == 2 ? vr[2].z : vr[2].w;
      float e3 = c == 0 ? vr[3].x : c == 1 ? vr[3].y : c == 2 ? vr[3].z : vr[3].w;
      half4v hv = {(_Float16)e0, (_Float16)e1, (_Float16)e2, (_Float16)e3};
      *(half4v*)&Vt[bufi][(vtx * 4 + c) * SH + vty * 4] = hv;
    }
  };

  for (int half = 0; half < 2; ++half) {
    const int rt = half ? (31 - (int)blockIdx.x) : (int)blockIdx.x;
    const int i0 = rt * TM;
    const int nt = rt + 1;       // causal j-tiles
    __syncthreads();             // close previous half (full drain, 1x per half)

    float4 kr[4], vr[4];
    // ---- prologue: issue K0 loads first, hide under Q staging ----
    loadK(0, kr);
    // stage Q (fp32 -> fp16 LDS)
#pragma unroll
    for (int it = 0; it < 4; ++it) {
      int idx = t + 256 * it;
      int r = idx >> 4, c = idx & 15;
      float4 qv = q4[(((size_t)b * LL + i0 + r) * HH + h) * 16 + c];
      half4v hq = {(_Float16)qv.x, (_Float16)qv.y, (_Float16)qv.z, (_Float16)qv.w};
      *(half4v*)&Qh[r * SH + c * 4] = hq;
    }
    // per-row sigma transform
    if (t < TM) {
      float sg = sgg[((size_t)b * LL + (i0 + t)) * HH + h];
      float sd = 1.0f / (1.0f + __expf(-5.0f * sg)) + 1e-5f;
      float sv = expm1f(sd * LN3);
      s_sigv[t] = sv;
      s_pinv[t] = INV_SQRT_2PI / sv;
      s_c2[t] = 0.5f / (sv * sv);
    }
    writeK(0, kr);
    barrier_release();

    // ================= pass 1: row sums (2-phase pipelined) =================
    float lsum[4] = {0.f, 0.f, 0.f, 0.f};
    int cur = 0;
    for (int jt = 0; jt < nt; ++jt) {
      const bool more = (jt + 1 < nt);
      if (more) loadK((jt + 1) * TN, kr);          // prefetch next tile
      floatx4 acc[4] = {{0.f, 0.f, 0.f, 0.f}, {0.f, 0.f, 0.f, 0.f},
                        {0.f, 0.f, 0.f, 0.f}, {0.f, 0.f, 0.f, 0.f}};
#pragma unroll
      for (int ks = 0; ks < 2; ++ks) {
        half8v a = *(half8v*)&Qh[(w * 16 + l15) * SH + ks * 32 + quad * 8];
#pragma unroll
        for (int f = 0; f < 4; ++f) {
          half8v bf = *(half8v*)&Kh[cur][(f * 16 + l15) * SH + ks * 32 + quad * 8];
          acc[f] = __builtin_amdgcn_mfma_f32_16x16x32_f16(a, bf, acc[f], 0, 0, 0);
        }
      }
      const int j0 = jt * TN;
#pragma unroll
      for (int f = 0; f < 4; ++f) {
        int j = j0 + f * 16 + l15;
#pragma unroll
        for (int r = 0; r < 4; ++r) {
          int i = i0 + w * 16 + quad * 4 + r;
          lsum[r] += (j <= i) ? __expf(acc[f][r] * SCALE) : 0.f;
        }
      }
      if (more) {
        writeK(cur ^ 1, kr);     // other buffer: prev readers done at last barrier
        barrier_release();       // one barrier per interval, no vmcnt drain
        cur ^= 1;
      }
    }
#pragma unroll
    for (int r = 0; r < 4; ++r) {
      lsum[r] += __shfl_xor(lsum[r], 1);
      lsum[r] += __shfl_xor(lsum[r], 2);
      lsum[r] += __shfl_xor(lsum[r], 4);
      lsum[r] += __shfl_xor(lsum[r], 8);
    }
    float linv[4];
#pragma unroll
    for (int r = 0; r < 4; ++r) linv[r] = 1.0f / lsum[r];

    // ================= pass 2: series + PV (2-phase pipelined) =================
    floatx4 Oacc[4] = {{0.f, 0.f, 0.f, 0.f}, {0.f, 0.f, 0.f, 0.f},
                       {0.f, 0.f, 0.f, 0.f}, {0.f, 0.f, 0.f, 0.f}};
    loadK(0, kr);
    loadV(0, vr);
    __syncthreads();             // pass1 Kh readers done before overwrite
    writeK(0, kr);
    writeV(0, vr);
    barrier_release();
    cur = 0;
    for (int jt = 0; jt < nt; ++jt) {
      const bool more = (jt + 1 < nt);
      const int j0 = jt * TN;
      if (more) {                // prefetch next tile into regs
        loadK((jt + 1) * TN, kr);
        loadV((jt + 1) * TN, vr);
      }
      // QK on current buffer
      floatx4 acc[4] = {{0.f, 0.f, 0.f, 0.f}, {0.f, 0.f, 0.f, 0.f},
                        {0.f, 0.f, 0.f, 0.f}, {0.f, 0.f, 0.f, 0.f}};
#pragma unroll
      for (int ks = 0; ks < 2; ++ks) {
        half8v a = *(half8v*)&Qh[(w * 16 + l15) * SH + ks * 32 + quad * 8];
#pragma unroll
        for (int f = 0; f < 4; ++f) {
          half8v bf = *(half8v*)&Kh[cur][(f * 16 + l15) * SH + ks * 32 + quad * 8];
          acc[f] = __builtin_amdgcn_mfma_f32_16x16x32_f16(a, bf, acc[f], 0, 0, 0);
        }
      }
      // P = exp(s*scale)*linv -> Ph (wave-local rows; no barrier needed)
#pragma unroll
      for (int f = 0; f < 4; ++f) {
        int j = j0 + f * 16 + l15;
#pragma unroll
        for (int r = 0; r < 4; ++r) {
          int i = i0 + w * 16 + quad * 4 + r;
          float p = (j <= i) ? __expf(acc[f][r] * SCALE) * linv[r] : 0.f;
          Ph[(w * 16 + quad * 4 + r) * SH + f * 16 + l15] = (_Float16)p;
        }
      }
      // series store: wave-local readback, fire-and-forget (never drained in-loop)
#pragma unroll
      for (int rnd = 0; rnd < 2; ++rnd) {
        int row = w * 16 + rnd * 8 + (lane >> 3);
        int c8 = lane & 7;
        half8v p = *(half8v*)&Ph[row * SH + c8 * 8];
        floatx4 lo = {(float)p[0], (float)p[1], (float)p[2], (float)p[3]};
        floatx4 hi = {(float)p[4], (float)p[5], (float)p[6], (float)p[7]};
        size_t off = SERIES_BASE + ((size_t)bh * LL + i0 + row) * LL + j0 + c8 * 8;
        *(floatx4*)&out[off] = lo;
        *(floatx4*)&out[off + 4] = hi;
      }
      // PV: O += P(own rows) * V
#pragma unroll
      for (int ks = 0; ks < 2; ++ks) {
        half8v a = *(half8v*)&Ph[(w * 16 + l15) * SH + ks * 32 + quad * 8];
#pragma unroll
        for (int f = 0; f < 4; ++f) {
          half8v bv = *(half8v*)&Vt[cur][(f * 16 + l15) * SH + ks * 32 + quad * 8];
          Oacc[f] = __builtin_amdgcn_mfma_f32_16x16x32_f16(a, bv, Oacc[f], 0, 0, 0);
        }
      }
      if (more) {
        writeK(cur ^ 1, kr);
        writeV(cur ^ 1, vr);
        barrier_release();
        cur ^= 1;
      }
    }
    // ---- V output (already normalized) ----
#pragma unroll
    for (int f = 0; f < 4; ++f) {
#pragma unroll
      for (int r = 0; r < 4; ++r) {
        int i = i0 + w * 16 + quad * 4 + r;
        out[(((size_t)b * LL + i) * HH + h) * EE + f * 16 + l15] = Oacc[f][r];
      }
    }
    // ---- prior + sig full rows (serial tail, proven best placement) ----
    for (int idx = t; idx < TM * 512; idx += 256) {
      int rr = idx >> 9, jq = idx & 511;
      float iv = s_pinv[rr], c2 = s_c2[rr], sv = s_sigv[rr];
      float fi = (float)(i0 + rr);
      float d0 = fi - (float)(jq * 4);
      float d1 = d0 - 1.0f, d2 = d0 - 2.0f, d3 = d0 - 3.0f;
      floatx4 pr;
      pr.x = iv * __expf(-d0 * d0 * c2);
      pr.y = iv * __expf(-d1 * d1 * c2);
      pr.z = iv * __expf(-d2 * d2 * c2);
      pr.w = iv * __expf(-d3 * d3 * c2);
      size_t off = ((size_t)bh * LL + (i0 + rr)) * LL + jq * 4;
      *(floatx4*)&out[PRIOR_BASE + off] = pr;
      floatx4 sg4 = {sv, sv, sv, sv};
      *(floatx4*)&out[SIG_BASE + off] = sg4;
    }
    // ---- series zero-fill (beyond causal tiles) ----
    {
      int jz = nt * TN;
      int nz4 = (LL - jz) >> 2;
      if (nz4 > 0) {
        const floatx4 z = {0.f, 0.f, 0.f, 0.f};
        for (int rr = 0; rr < TM; ++rr) {
          float* rowp = &out[SERIES_BASE + ((size_t)bh * LL + (i0 + rr)) * LL + jz];
          for (int c = t; c < nz4; c += 256) {
            *(floatx4*)&rowp[c * 4] = z;
          }
        }
      }
    }
  }
}

extern "C" void kernel_launch(void* const* d_in, const int* in_sizes, int n_in,
                              void* d_out, int out_size, void* d_ws, size_t ws_size,
                              hipStream_t stream) {
  const float* q = (const float*)d_in[0];
  const float* k = (const float*)d_in[1];
  const float* v = (const float*)d_in[2];
  const float* sg = (const float*)d_in[3];
  float* out = (float*)d_out;
  dim3 grid(LL / TM / 2, BB * HH);  // 16 x 32 = 512 blocks, strip-paired
  anomaly_attn<<<grid, 256, 0, stream>>>(q, k, v, sg, out);
}

// Round 8
// 1686.837 us; speedup vs baseline: 1.0802x; 1.0016x over previous
//
#include <hip/hip_runtime.h>
#include <math.h>

#define BB 4
#define LL 2048
#define HH 8
#define EE 64
#define TM 64
#define TN 64
#define SH 72   // fp16 LDS row stride

typedef _Float16 half4v __attribute__((ext_vector_type(4)));
typedef _Float16 half8v __attribute__((ext_vector_type(8)));
typedef float floatx4 __attribute__((ext_vector_type(4)));

static constexpr float SCALE = 0.125f;                    // 1/sqrt(64)
static constexpr float LN3 = 1.0986122886681098f;
static constexpr float INV_SQRT_2PI = 0.3989422804014327f;
static constexpr size_t NMAT = (size_t)BB * HH * LL * LL;
static constexpr size_t SERIES_BASE = (size_t)BB * LL * HH * EE;
static constexpr size_t PRIOR_BASE = SERIES_BASE + NMAT;
static constexpr size_t SIG_BASE = PRIOR_BASE + NMAT;

// Producer-release barrier (R7-proven): LDS writes visible + sync, but NO
// vmcnt drain -> global stores / prefetch loads stay in flight across it.
__device__ __forceinline__ void barrier_release() {
  asm volatile("s_waitcnt lgkmcnt(0)" ::: "memory");
  __builtin_amdgcn_s_barrier();
  __builtin_amdgcn_sched_barrier(0);
}

// R7 pipeline + occupancy push: Q in registers (no Qh LDS), 46.8 KB LDS ->
// 3 blocks/CU (12 waves/CU), 1024 unpaired blocks dispatched big-rt-first.
__global__ __launch_bounds__(256, 3)
void anomaly_attn(const float* __restrict__ qg,
                  const float* __restrict__ kg,
                  const float* __restrict__ vg,
                  const float* __restrict__ sgg,
                  float* __restrict__ out) {
  __shared__ __attribute__((aligned(16))) _Float16 Kh[2][TN * SH];    // 18432 B
  __shared__ __attribute__((aligned(16))) _Float16 Vt[2][EE * SH];    // 18432 B
  __shared__ __attribute__((aligned(16))) _Float16 Ph[TM * SH];       //  9216 B
  __shared__ float s_sigv[TM], s_pinv[TM], s_c2[TM];

  const int t = threadIdx.x;
  const int lane = t & 63;
  const int w = t >> 6;          // wave id 0..3 -> rows w*16..w*16+15
  const int quad = lane >> 4;    // 0..3
  const int l15 = lane & 15;
  const int bh = blockIdx.x;     // bh fastest -> same-rt blocks dispatch together
  const int b = bh >> 3, h = bh & 7;
  const int rt = 31 - (int)blockIdx.y;   // big tiles dispatch FIRST
  const int i0 = rt * TM;
  const int nt = rt + 1;         // causal j-tiles
  const float4* q4 = (const float4*)qg;
  const float4* k4 = (const float4*)kg;
  const float4* v4 = (const float4*)vg;

  // staging geometry (block-cooperative, R0/R7 partition)
  const int kr_r0 = t >> 4, kr_c = t & 15;        // K: 4 chunks of (r,c)
  const int vtx = t & 15, vty = t >> 4;           // V: 4x4 micro-transpose

  auto loadK = [&](int j0, float4* kr) {
#pragma unroll
    for (int it = 0; it < 4; ++it)
      kr[it] = k4[(((size_t)b * LL + j0 + kr_r0 + 16 * it) * HH + h) * 16 + kr_c];
  };
  auto writeK = [&](int bufi, const float4* kr) {
#pragma unroll
    for (int it = 0; it < 4; ++it) {
      half4v hk = {(_Float16)kr[it].x, (_Float16)kr[it].y,
                   (_Float16)kr[it].z, (_Float16)kr[it].w};
      *(half4v*)&Kh[bufi][(kr_r0 + 16 * it) * SH + kr_c * 4] = hk;
    }
  };
  auto loadV = [&](int j0, float4* vr) {
#pragma unroll
    for (int rr = 0; rr < 4; ++rr)
      vr[rr] = v4[(((size_t)b * LL + j0 + vty * 4 + rr) * HH + h) * 16 + vtx];
  };
  auto writeV = [&](int bufi, const float4* vr) {
#pragma unroll
    for (int c = 0; c < 4; ++c) {
      float e0 = c == 0 ? vr[0].x : c == 1 ? vr[0].y : c == 2 ? vr[0].z : vr[0].w;
      float e1 = c == 0 ? vr[1].x : c == 1 ? vr[1].y : c == 2 ? vr[1].z : vr[1].w;
      float e2 = c == 0 ? vr[2].x : c == 1 ? vr[2].y : c == 2 ? vr[2].z : vr[2].w;
      float e3 = c == 0 ? vr[3].x : c == 1 ? vr[3].y : c == 2 ? vr[3].z : vr[3].w;
      half4v hv = {(_Float16)e0, (_Float16)e1, (_Float16)e2, (_Float16)e3};
      *(half4v*)&Vt[bufi][(vtx * 4 + c) * SH + vty * 4] = hv;
    }
  };

  float4 kr[4], vr[4];
  loadK(0, kr);                  // K0 loads issue first

  // ---- Q fragments straight to registers (rows w*16+l15, once per block) ----
  half8v qa[2];
  {
    const float4* qp = &q4[(((size_t)b * LL + i0 + w * 16 + l15) * HH + h) * 16];
#pragma unroll
    for (int ks = 0; ks < 2; ++ks) {
      float4 x = qp[ks * 8 + quad * 2];
      float4 y = qp[ks * 8 + quad * 2 + 1];
      qa[ks] = (half8v){(_Float16)x.x, (_Float16)x.y, (_Float16)x.z, (_Float16)x.w,
                        (_Float16)y.x, (_Float16)y.y, (_Float16)y.z, (_Float16)y.w};
    }
  }
  // ---- per-row sigma transform (for prior/sig tail) ----
  if (t < TM) {
    float sg = sgg[((size_t)b * LL + (i0 + t)) * HH + h];
    float sd = 1.0f / (1.0f + __expf(-5.0f * sg)) + 1e-5f;
    float sv = expm1f(sd * LN3);
    s_sigv[t] = sv;
    s_pinv[t] = INV_SQRT_2PI / sv;
    s_c2[t] = 0.5f / (sv * sv);
  }
  writeK(0, kr);
  barrier_release();

  // ================= pass 1: row sums (2-phase pipelined) =================
  float lsum[4] = {0.f, 0.f, 0.f, 0.f};
  int cur = 0;
  for (int jt = 0; jt < nt; ++jt) {
    const bool more = (jt + 1 < nt);
    if (more) loadK((jt + 1) * TN, kr);          // prefetch next tile
    floatx4 acc[4] = {{0.f, 0.f, 0.f, 0.f}, {0.f, 0.f, 0.f, 0.f},
                      {0.f, 0.f, 0.f, 0.f}, {0.f, 0.f, 0.f, 0.f}};
#pragma unroll
    for (int ks = 0; ks < 2; ++ks) {
#pragma unroll
      for (int f = 0; f < 4; ++f) {
        half8v bf = *(half8v*)&Kh[cur][(f * 16 + l15) * SH + ks * 32 + quad * 8];
        acc[f] = __builtin_amdgcn_mfma_f32_16x16x32_f16(qa[ks], bf, acc[f], 0, 0, 0);
      }
    }
    const int j0 = jt * TN;
#pragma unroll
    for (int f = 0; f < 4; ++f) {
      int j = j0 + f * 16 + l15;
#pragma unroll
      for (int r = 0; r < 4; ++r) {
        int i = i0 + w * 16 + quad * 4 + r;
        lsum[r] += (j <= i) ? __expf(acc[f][r] * SCALE) : 0.f;
      }
    }
    if (more) {
      writeK(cur ^ 1, kr);
      barrier_release();         // one barrier per interval, no vmcnt drain
      cur ^= 1;
    }
  }
#pragma unroll
  for (int r = 0; r < 4; ++r) {
    lsum[r] += __shfl_xor(lsum[r], 1);
    lsum[r] += __shfl_xor(lsum[r], 2);
    lsum[r] += __shfl_xor(lsum[r], 4);
    lsum[r] += __shfl_xor(lsum[r], 8);
  }
  float linv[4];
#pragma unroll
  for (int r = 0; r < 4; ++r) linv[r] = 1.0f / lsum[r];

  // ================= pass 2: series + PV (2-phase pipelined) =================
  floatx4 Oacc[4] = {{0.f, 0.f, 0.f, 0.f}, {0.f, 0.f, 0.f, 0.f},
                     {0.f, 0.f, 0.f, 0.f}, {0.f, 0.f, 0.f, 0.f}};
  loadK(0, kr);
  loadV(0, vr);
  __syncthreads();               // pass1 Kh readers done before overwrite
  writeK(0, kr);
  writeV(0, vr);
  barrier_release();
  cur = 0;
  for (int jt = 0; jt < nt; ++jt) {
    const bool more = (jt + 1 < nt);
    const int j0 = jt * TN;
    if (more) {
      loadK((jt + 1) * TN, kr);
      loadV((jt + 1) * TN, vr);
    }
    // QK on current buffer
    floatx4 acc[4] = {{0.f, 0.f, 0.f, 0.f}, {0.f, 0.f, 0.f, 0.f},
                      {0.f, 0.f, 0.f, 0.f}, {0.f, 0.f, 0.f, 0.f}};
#pragma unroll
    for (int ks = 0; ks < 2; ++ks) {
#pragma unroll
      for (int f = 0; f < 4; ++f) {
        half8v bf = *(half8v*)&Kh[cur][(f * 16 + l15) * SH + ks * 32 + quad * 8];
        acc[f] = __builtin_amdgcn_mfma_f32_16x16x32_f16(qa[ks], bf, acc[f], 0, 0, 0);
      }
    }
    // P = exp(s*scale)*linv -> Ph (wave-local rows; no barrier needed)
#pragma unroll
    for (int f = 0; f < 4; ++f) {
      int j = j0 + f * 16 + l15;
#pragma unroll
      for (int r = 0; r < 4; ++r) {
        int i = i0 + w * 16 + quad * 4 + r;
        float p = (j <= i) ? __expf(acc[f][r] * SCALE) * linv[r] : 0.f;
        Ph[(w * 16 + quad * 4 + r) * SH + f * 16 + l15] = (_Float16)p;
      }
    }
    // series store: wave-local readback, fire-and-forget
#pragma unroll
    for (int rnd = 0; rnd < 2; ++rnd) {
      int row = w * 16 + rnd * 8 + (lane >> 3);
      int c8 = lane & 7;
      half8v p = *(half8v*)&Ph[row * SH + c8 * 8];
      floatx4 lo = {(float)p[0], (float)p[1], (float)p[2], (float)p[3]};
      floatx4 hi = {(float)p[4], (float)p[5], (float)p[6], (float)p[7]};
      size_t off = SERIES_BASE + ((size_t)bh * LL + i0 + row) * LL + j0 + c8 * 8;
      *(floatx4*)&out[off] = lo;
      *(floatx4*)&out[off + 4] = hi;
    }
    // PV: O += P(own rows) * V
#pragma unroll
    for (int ks = 0; ks < 2; ++ks) {
      half8v a = *(half8v*)&Ph[(w * 16 + l15) * SH + ks * 32 + quad * 8];
#pragma unroll
      for (int f = 0; f < 4; ++f) {
        half8v bv = *(half8v*)&Vt[cur][(f * 16 + l15) * SH + ks * 32 + quad * 8];
        Oacc[f] = __builtin_amdgcn_mfma_f32_16x16x32_f16(a, bv, Oacc[f], 0, 0, 0);
      }
    }
    if (more) {
      writeK(cur ^ 1, kr);
      writeV(cur ^ 1, vr);
      barrier_release();
      cur ^= 1;
    }
  }
  // ---- V output (already normalized) ----
#pragma unroll
  for (int f = 0; f < 4; ++f) {
#pragma unroll
    for (int r = 0; r < 4; ++r) {
      int i = i0 + w * 16 + quad * 4 + r;
      out[(((size_t)b * LL + i) * HH + h) * EE + f * 16 + l15] = Oacc[f][r];
    }
  }
  // ---- prior + sig full rows (serial tail, proven best placement) ----
  for (int idx = t; idx < TM * 512; idx += 256) {
    int rr = idx >> 9, jq = idx & 511;
    float iv = s_pinv[rr], c2 = s_c2[rr], sv = s_sigv[rr];
    float fi = (float)(i0 + rr);
    float d0 = fi - (float)(jq * 4);
    float d1 = d0 - 1.0f, d2 = d0 - 2.0f, d3 = d0 - 3.0f;
    floatx4 pr;
    pr.x = iv * __expf(-d0 * d0 * c2);
    pr.y = iv * __expf(-d1 * d1 * c2);
    pr.z = iv * __expf(-d2 * d2 * c2);
    pr.w = iv * __expf(-d3 * d3 * c2);
    size_t off = ((size_t)bh * LL + (i0 + rr)) * LL + jq * 4;
    *(floatx4*)&out[PRIOR_BASE + off] = pr;
    floatx4 sg4 = {sv, sv, sv, sv};
    *(floatx4*)&out[SIG_BASE + off] = sg4;
  }
  // ---- series zero-fill (beyond causal tiles) ----
  {
    int jz = nt * TN;
    int nz4 = (LL - jz) >> 2;
    if (nz4 > 0) {
      const floatx4 z = {0.f, 0.f, 0.f, 0.f};
      for (int rr = 0; rr < TM; ++rr) {
        float* rowp = &out[SERIES_BASE + ((size_t)bh * LL + (i0 + rr)) * LL + jz];
        for (int c = t; c < nz4; c += 256) {
          *(floatx4*)&rowp[c * 4] = z;
        }
      }
    }
  }
}

extern "C" void kernel_launch(void* const* d_in, const int* in_sizes, int n_in,
                              void* d_out, int out_size, void* d_ws, size_t ws_size,
                              hipStream_t stream) {
  const float* q = (const float*)d_in[0];
  const float* k = (const float*)d_in[1];
  const float* v = (const float*)d_in[2];
  const float* sg = (const float*)d_in[3];
  float* out = (float*)d_out;
  // 32 bh (x, fastest) x 32 row-tiles (y, rt = 31-y so biggest dispatch first)
  dim3 grid(BB * HH, LL / TM);
  anomaly_attn<<<grid, 256, 0, stream>>>(q, k, v, sg, out);
}